// Round 19
// baseline (444.958 us; speedup 1.0000x reference)
//
#include <hip/hip_runtime.h>
#include <hip/hip_bf16.h>
#include <math.h>

// HelicalGNNFrontend: 2-layer GATv2 (heads=1, self-loops, mean loop edge_attr)
// N=50000, E=800000, NODE_DIM=HID=128, EDGE_DIM=32.
//
// Round 19: fused kernel rebuilt around MFMA. Per 16-edge batch:
// EPROJ = EA[16][32] @ We[32][128] via 8x mfma_f32_16x16x32_f16 (2 passes).
// Lane owns (4 edges of group lk) x (8 dims {li+16n}) = MFMA C layout.
// xl/xr/h stored DIM-PERMUTED packed f16 (pd=(d&15)*8+(d>>4)); linm epilogue
// writes it natively (in-lane pairs, no shfl); layer-2 GEMM uses K-permuted
// Wt2 (GEMM invariant under shared K-permutation). att/bo pre-permuted.
// Logit reduce: 4 shfl over li; batch max: 2 shfl; acc/eps/denom reduced
// across lk once per node. Tail edges zero-padded (eproj row=0, logit=-inf).

#define HIP_N 50000
#define HIP_E 800000
#define HIP_H 128
#define HIP_ED 32
#define NEG_SLOPE 0.2f
#define RESCALE_THR_LOG2 11.5416f   // 8 / ln2
#define LINM 3125                   // 50000 / 16 M-tiles
#define SCATB ((HIP_E + 255) / 256) // 3125 scatter blocks
#define INV_LN2 1.4426950408889634f

typedef __fp16 h2 __attribute__((ext_vector_type(2)));
typedef _Float16 half8 __attribute__((ext_vector_type(8)));
typedef float f32x4 __attribute__((ext_vector_type(4)));

__device__ __forceinline__ h2 u2h(unsigned int u) {
    union { unsigned int u; h2 h; } c; c.u = u; return c.h;
}
__device__ __forceinline__ unsigned int pkh(float a, float b) {
    union { h2 h; unsigned int u; } c;
    c.h = __builtin_amdgcn_cvt_pkrtz(a, b);
    return c.u;
}
__device__ __forceinline__ float hlo(unsigned int u) { return (float)u2h(u).x; }
__device__ __forceinline__ float hhi(unsigned int u) { return (float)u2h(u).y; }
__device__ __forceinline__ half8 u4h8(uint4 u) {
    union { uint4 u; half8 h; } c; c.u = u; return c.h;
}

__device__ __forceinline__ int fetch_idx(const int* __restrict__ ei, int is32, long long pos) {
    return is32 ? ei[pos] : ei[2 * pos];  // little-endian low word for int64
}

// per-wave edge-dtype detect: probe ei[2e+1] (valid flat index in BOTH
// layouts). int64 -> high words, all zero. int32 -> node ids, ~never all 0.
__device__ __forceinline__ int wave_is32(const int* __restrict__ ei, int e) {
    int probe = (e < HIP_E) ? ei[2 * (long long)e + 1] : 0;
    return __any(probe != 0);
}

// ---------------- mega prep kernel (128 threads/block) ----------------
// [0,256): compose W_emb@{Wl1,Wr1} -> Wt1 transposed f16 (original K order)
// 256..259: biases b1/b2
// [260,388): Wt2 K-PERMUTED transpose -> f16
// [388,396): WemB1/2 MFMA B-fragments (8 tiles x 64 lanes x uint4, per layer)
// 396..399: att_p1, bo_p1, att_p2, bo_p2 (permuted; att scaled by 1/ln2)
// [400, ...): zero deg
#define PREP_NB (400 + (HIP_N + 127) / 128)

__global__ __launch_bounds__(128) void k_prep(
    const float* __restrict__ Wemb, const float* __restrict__ bemb,
    const float* __restrict__ Wl1, const float* __restrict__ bl1,
    const float* __restrict__ Wr1,
    const float* __restrict__ Wl2, const float* __restrict__ bl2,
    const float* __restrict__ Wr2,
    const float* __restrict__ We1, const float* __restrict__ We2,
    const float* __restrict__ att1, const float* __restrict__ bo1,
    const float* __restrict__ att2, const float* __restrict__ bo2,
    unsigned short* __restrict__ Wt1, unsigned short* __restrict__ Wt2,
    float* __restrict__ b1, float* __restrict__ b2,
    uint4* __restrict__ WemB1, uint4* __restrict__ WemB2,
    float* __restrict__ attp1, float* __restrict__ bop1,
    float* __restrict__ attp2, float* __restrict__ bop2,
    int* __restrict__ deg) {
    int b = blockIdx.x, t = threadIdx.x;
    if (b < 256) {
        int r = b & 127;
        const float* W = (b < 128) ? Wl1 : Wr1;
        int nofs = (b < 128) ? 0 : 128;
        float acc = 0.f;
        for (int k = 0; k < 128; ++k) acc += Wemb[r * 128 + k] * W[k * 128 + t];
        union { __fp16 h; unsigned short s; } cv;
        cv.h = (__fp16)acc;
        Wt1[(size_t)(nofs + t) * 128 + r] = cv.s;   // Wt1[n][k] = Wf[k][n]
    } else if (b == 256) {
        float acc = bl1[t];
        for (int k = 0; k < 128; ++k) acc += bemb[k] * Wl1[k * 128 + t];
        b1[t] = acc;
    } else if (b == 257) {
        float acc = 0.f;
        for (int k = 0; k < 128; ++k) acc += bemb[k] * Wr1[k * 128 + t];
        b1[128 + t] = acc;
    } else if (b == 258) {
        b2[t] = bl2[t];
    } else if (b == 259) {
        b2[128 + t] = 0.f;
    } else if (b < 388) {
        int pk = b - 260;                           // permuted k index
        int d = (pk >> 3) + ((pk & 7) << 4);        // original k row
        float vl = Wl2[d * 128 + t], vr = Wr2[d * 128 + t];
        union { __fp16 h; unsigned short s; } c1, c2;
        c1.h = (__fp16)vl; c2.h = (__fp16)vr;
        Wt2[(size_t)t * 128 + pk] = c1.s;
        Wt2[(size_t)(128 + t) * 128 + pk] = c2.s;
    } else if (b < 396) {
        int idx = (b - 388) * 128 + t;              // [0, 1024)
        int layer = idx >> 9, rem = idx & 511;
        int n = rem >> 6, ll = rem & 63;
        int col = 16 * n + (ll & 15);
        int kb = (ll >> 4) * 8;
        const float* We = layer ? We2 : We1;
        uint4 v = make_uint4(
            pkh(We[(kb + 0) * 128 + col], We[(kb + 1) * 128 + col]),
            pkh(We[(kb + 2) * 128 + col], We[(kb + 3) * 128 + col]),
            pkh(We[(kb + 4) * 128 + col], We[(kb + 5) * 128 + col]),
            pkh(We[(kb + 6) * 128 + col], We[(kb + 7) * 128 + col]));
        (layer ? WemB2 : WemB1)[rem] = v;
    } else if (b < 400) {
        int which = b - 396;                        // 0..3
        int li = t >> 3, q = t & 7;
        int src = li + 16 * q;
        if (which == 0)      attp1[t] = att1[src] * INV_LN2;
        else if (which == 1) bop1[t]  = bo1[src];
        else if (which == 2) attp2[t] = att2[src] * INV_LN2;
        else                 bop2[t]  = bo2[src];
    } else {
        int i = (b - 400) * 128 + t;
        if (i < HIP_N) deg[i] = 0;
    }
}

// ---------------- CSR build ----------------
__global__ void k_hist(const int* __restrict__ ei, int* __restrict__ deg) {
    int e = blockIdx.x * blockDim.x + threadIdx.x;
    int is32 = wave_is32(ei, e);
    if (e < HIP_E) {
        int d = fetch_idx(ei, is32, (long long)HIP_E + e);
        atomicAdd(&deg[d], 1);
    }
}

#define SCAN_TILE 1024
#define SCAN_NB ((HIP_N + SCAN_TILE - 1) / SCAN_TILE)   // 49

__global__ __launch_bounds__(256) void k_scan1(const int* __restrict__ deg,
                                               int* __restrict__ bsums) {
    __shared__ int ws[4];
    int b = blockIdx.x, t = threadIdx.x;
    int base = b * SCAN_TILE;
    int v = 0;
#pragma unroll
    for (int j = 0; j < 4; ++j) {
        int i = base + t + 256 * j;
        if (i < HIP_N) v += deg[i];
    }
#pragma unroll
    for (int off = 32; off > 0; off >>= 1) v += __shfl_xor(v, off);
    int lane = t & 63, wid = t >> 6;
    if (lane == 0) ws[wid] = v;
    __syncthreads();
    if (t == 0) bsums[b] = ws[0] + ws[1] + ws[2] + ws[3];
}

__global__ __launch_bounds__(1024) void k_scan3(const int* __restrict__ deg,
                                                const int* __restrict__ bsums,
                                                int* __restrict__ offs,
                                                int* __restrict__ cursor) {
    __shared__ int wsum[16];
    __shared__ int bbase_sh;
    int b = blockIdx.x, t = threadIdx.x;
    int i = b * SCAN_TILE + t;
    int lane = t & 63, wid = t >> 6;
    if (wid == 0) {                      // prefix of bsums[0..b-1]
        int v = (lane < SCAN_NB && lane < b) ? bsums[lane] : 0;
#pragma unroll
        for (int off = 32; off > 0; off >>= 1) v += __shfl_xor(v, off);
        if (lane == 0) bbase_sh = v;
    }
    int v = (i < HIP_N) ? deg[i] : 0;
    int incl = v;
#pragma unroll
    for (int off = 1; off < 64; off <<= 1) {
        int u = __shfl_up(incl, off);
        if (lane >= off) incl += u;
    }
    if (lane == 63) wsum[wid] = incl;
    __syncthreads();
    if (wid == 0 && lane < 16) {
        int w = wsum[lane];
#pragma unroll
        for (int off = 1; off < 16; off <<= 1) {
            int u = __shfl_up(w, off);
            if (lane >= off) w += u;
        }
        wsum[lane] = w;   // inclusive over waves
    }
    __syncthreads();
    int baseadd = bbase_sh + (wid > 0 ? wsum[wid - 1] : 0);
    int excl = baseadd + incl - v;
    if (i < HIP_N) {
        offs[i] = excl;
        cursor[i] = excl;
        if (i == HIP_N - 1) offs[HIP_N] = excl + v;
    }
}

// ---------------- MFMA dual-GEMM body (templated A dtype) ----------------
// out[xl|xr] = A[50k,128] @ Wt^T + bias; outputs DIM-PERMUTED packed f16.
template <bool AHALF>
__device__ __forceinline__ void linm_body(const float* __restrict__ Af,
                                          const unsigned int* __restrict__ Ah,
                                          const unsigned short* __restrict__ Wt,
                                          const float* __restrict__ bias,
                                          unsigned int* __restrict__ xlh,
                                          unsigned int* __restrict__ xrh, int blk) {
    int tid = threadIdx.x;
    int wid = tid >> 6, l = tid & 63;
    int li = l & 15, lk = l >> 4;          // A row / C col = li; k-group = lk
    int rowA = blk * 16 + li;

    f32x4 acc0 = {0.f, 0.f, 0.f, 0.f};
    f32x4 acc1 = {0.f, 0.f, 0.f, 0.f};
    f32x4 acc2 = {0.f, 0.f, 0.f, 0.f};
    f32x4 acc3 = {0.f, 0.f, 0.f, 0.f};

#pragma unroll
    for (int ks = 0; ks < 4; ++ks) {
        int kb = ks * 32 + lk * 8;
        half8 afrag;
        if (AHALF) {
            afrag = u4h8(*(const uint4*)(Ah + (size_t)rowA * 64 + (kb >> 1)));
        } else {
            const float4* ap = (const float4*)(Af + (size_t)rowA * 128 + kb);
            float4 a0 = ap[0], a1 = ap[1];
            afrag = u4h8(make_uint4(pkh(a0.x, a0.y), pkh(a0.z, a0.w),
                                    pkh(a1.x, a1.y), pkh(a1.z, a1.w)));
        }
        int nbase = wid * 64 + li;
        half8 b0 = u4h8(*(const uint4*)(Wt + (size_t)(nbase +  0) * 128 + kb));
        half8 b1 = u4h8(*(const uint4*)(Wt + (size_t)(nbase + 16) * 128 + kb));
        half8 b2 = u4h8(*(const uint4*)(Wt + (size_t)(nbase + 32) * 128 + kb));
        half8 b3 = u4h8(*(const uint4*)(Wt + (size_t)(nbase + 48) * 128 + kb));
        acc0 = __builtin_amdgcn_mfma_f32_16x16x32_f16(afrag, b0, acc0, 0, 0, 0);
        acc1 = __builtin_amdgcn_mfma_f32_16x16x32_f16(afrag, b1, acc1, 0, 0, 0);
        acc2 = __builtin_amdgcn_mfma_f32_16x16x32_f16(afrag, b2, acc2, 0, 0, 0);
        acc3 = __builtin_amdgcn_mfma_f32_16x16x32_f16(afrag, b3, acc3, 0, 0, 0);
    }

    // epilogue: permuted packed store, pairs are IN-LANE (no shfl).
    // dim d = wid*64 + nt*16 + li -> pd = li*8 + (wid&1)*4 + nt
    unsigned int* outp = (wid < 2) ? xlh : xrh;
    int wsel = wid & 1;
    float bb0 = bias[wid * 64 +  0 + li];
    float bb1 = bias[wid * 64 + 16 + li];
    float bb2 = bias[wid * 64 + 32 + li];
    float bb3 = bias[wid * 64 + 48 + li];
#pragma unroll
    for (int r = 0; r < 4; ++r) {
        int rowg = blk * 16 + lk * 4 + r;
        float v0 = acc0[r] + bb0;
        float v1 = acc1[r] + bb1;
        float v2 = acc2[r] + bb2;
        float v3 = acc3[r] + bb3;
        uint2 st = make_uint2(pkh(v0, v1), pkh(v2, v3));
        *(uint2*)(outp + (size_t)rowg * 64 + li * 4 + wsel * 2) = st;
    }
}

// scatter body: e_src[pos]=src, ea_h[pos]= half2-packed ea row (64B)
__device__ __forceinline__ void scatter_body(const int* __restrict__ ei, int is32,
                                             int* __restrict__ cursor,
                                             int* __restrict__ e_src,
                                             const float* __restrict__ ea,
                                             unsigned int* __restrict__ ea_h, int e) {
    if (e < HIP_E) {
        int s = fetch_idx(ei, is32, e);
        int d = fetch_idx(ei, is32, (long long)HIP_E + e);
        int pos = atomicAdd(&cursor[d], 1);
        e_src[pos] = s;
        const float4* src4 = (const float4*)(ea + (size_t)e * HIP_ED);
        float4 s0 = src4[0], s1 = src4[1], s2 = src4[2], s3 = src4[3];
        float4 s4 = src4[4], s5 = src4[5], s6 = src4[6], s7 = src4[7];
        uint4* dst = (uint4*)(ea_h + (size_t)pos * 16);
        dst[0] = make_uint4(pkh(s0.x, s0.y), pkh(s0.z, s0.w),
                            pkh(s1.x, s1.y), pkh(s1.z, s1.w));
        dst[1] = make_uint4(pkh(s2.x, s2.y), pkh(s2.z, s2.w),
                            pkh(s3.x, s3.y), pkh(s3.z, s3.w));
        dst[2] = make_uint4(pkh(s4.x, s4.y), pkh(s4.z, s4.w),
                            pkh(s5.x, s5.y), pkh(s5.z, s5.w));
        dst[3] = make_uint4(pkh(s6.x, s6.y), pkh(s6.z, s6.w),
                            pkh(s7.x, s7.y), pkh(s7.z, s7.w));
    }
}

// fat kernel: blocks [0, LINM) do layer-1 MFMA lin; rest scatter
__global__ __launch_bounds__(256) void k_fat1(
    const float* __restrict__ x, const unsigned short* __restrict__ Wt1,
    const float* __restrict__ b1,
    unsigned int* __restrict__ xlh, unsigned int* __restrict__ xrh,
    const int* __restrict__ ei,
    int* __restrict__ cursor, int* __restrict__ e_src,
    const float* __restrict__ ea, unsigned int* __restrict__ ea_h) {
    if (blockIdx.x < LINM) {
        linm_body<false>(x, nullptr, Wt1, b1, xlh, xrh, blockIdx.x);
    } else {
        int e = (blockIdx.x - LINM) * 256 + threadIdx.x;
        int is32 = wave_is32(ei, e);
        scatter_body(ei, is32, cursor, e_src, ea, ea_h, e);
    }
}

// layer-2 lin: A = permuted packed-f16 h (matches K-permuted Wt2)
__global__ __launch_bounds__(256) void k_linm(const unsigned int* __restrict__ hh,
                                              const unsigned short* __restrict__ Wt,
                                              const float* __restrict__ bias,
                                              unsigned int* __restrict__ xlh,
                                              unsigned int* __restrict__ xrh) {
    linm_body<true>(nullptr, hh, Wt, bias, xlh, xrh, blockIdx.x);
}

// ---------------- fused per-node MFMA softmax + aggregation ----------------
// ONE 64-thread block per node. 16-edge batches: 8x mfma eproj (2 passes),
// lane (lk,li) owns 4 edges (lk*4+r) x 8 dims {li+16n}. xl/xr permuted f16.
template <int OUTH>
__global__ __launch_bounds__(64) void k_node_mfma(
    const int* __restrict__ offs, const int* __restrict__ e_src,
    const unsigned int* __restrict__ ea_h,
    const uint4* __restrict__ WemB, const float* __restrict__ att_p,
    const unsigned int* __restrict__ xlh, const unsigned int* __restrict__ xrh,
    const float* __restrict__ bo_p,
    unsigned int* __restrict__ houth, float* __restrict__ houtf) {
    int i = blockIdx.x;
    int l = threadIdx.x, li = l & 15, lk = l >> 4;

    // persistent per-lane data (dims {li+16n}, permuted chunk li*8..+8)
    float attv[8], xriv[8];
    {
        const float4* ap = (const float4*)(att_p + li * 8);
        float4 q0 = ap[0], q1 = ap[1];
        attv[0]=q0.x; attv[1]=q0.y; attv[2]=q0.z; attv[3]=q0.w;
        attv[4]=q1.x; attv[5]=q1.y; attv[6]=q1.z; attv[7]=q1.w;
        uint4 xr4 = *(const uint4*)(xrh + (size_t)i * 64 + li * 4);
        xriv[0]=hlo(xr4.x); xriv[1]=hhi(xr4.x); xriv[2]=hlo(xr4.y); xriv[3]=hhi(xr4.y);
        xriv[4]=hlo(xr4.z); xriv[5]=hhi(xr4.z); xriv[6]=hlo(xr4.w); xriv[7]=hhi(xr4.w);
    }

    int o0 = offs[i], o1 = offs[i + 1];
    int cnt = o1 - o0;

    float m = -1e30f, denom = 0.f;
    float acc[8] = {0,0,0,0,0,0,0,0};
    float eps[8] = {0,0,0,0,0,0,0,0};

    for (int base = o0; base < o1; base += 16) {
        // A-fragment: edge row = li, k slice = lk*8..+8
        int ea_e = base + li;
        uint4 au = (ea_e < o1) ? *(const uint4*)(ea_h + (size_t)ea_e * 16 + lk * 4)
                               : make_uint4(0, 0, 0, 0);
        half8 afrag = u4h8(au);

        // src ids + xl gathers for this group's 4 edges
        int sv[4]; int val[4]; uint4 xlu[4];
#pragma unroll
        for (int r = 0; r < 4; ++r) {
            int idx = base + lk * 4 + r;
            val[r] = idx < o1;
            sv[r] = val[r] ? e_src[idx] : 0;
        }
#pragma unroll
        for (int r = 0; r < 4; ++r)
            xlu[r] = *(const uint4*)(xlh + (size_t)sv[r] * 64 + li * 4);

        float p[4] = {0.f, 0.f, 0.f, 0.f};
#pragma unroll
        for (int pass = 0; pass < 2; ++pass) {
            const uint4* wb = WemB + pass * 256 + l;
            half8 bf0 = u4h8(wb[0]);
            half8 bf1 = u4h8(wb[64]);
            half8 bf2 = u4h8(wb[128]);
            half8 bf3 = u4h8(wb[192]);
            f32x4 c0 = {0,0,0,0}, c1 = {0,0,0,0}, c2 = {0,0,0,0}, c3 = {0,0,0,0};
            c0 = __builtin_amdgcn_mfma_f32_16x16x32_f16(afrag, bf0, c0, 0, 0, 0);
            c1 = __builtin_amdgcn_mfma_f32_16x16x32_f16(afrag, bf1, c1, 0, 0, 0);
            c2 = __builtin_amdgcn_mfma_f32_16x16x32_f16(afrag, bf2, c2, 0, 0, 0);
            c3 = __builtin_amdgcn_mfma_f32_16x16x32_f16(afrag, bf3, c3, 0, 0, 0);
#pragma unroll
            for (int nn = 0; nn < 4; ++nn) {
                int n = pass * 4 + nn;
                f32x4 C = (nn == 0) ? c0 : (nn == 1) ? c1 : (nn == 2) ? c2 : c3;
                float av = attv[n], xr_ = xriv[n];
#pragma unroll
                for (int r = 0; r < 4; ++r) {
                    unsigned int dw = ((const unsigned int*)&xlu[r])[n >> 1];
                    float xv = (n & 1) ? hhi(dw) : hlo(dw);
                    float v = xv + xr_ + C[r];
                    v = fmaxf(v, NEG_SLOPE * v);
                    p[r] += v * av;
                }
                eps[n] += C[0] + C[1] + C[2] + C[3];
            }
        }
        // reduce logits over the 16 li-lanes (4 interleaved chains)
#pragma unroll
        for (int off = 1; off <= 8; off <<= 1) {
            p[0] += __shfl_xor(p[0], off);
            p[1] += __shfl_xor(p[1], off);
            p[2] += __shfl_xor(p[2], off);
            p[3] += __shfl_xor(p[3], off);
        }
#pragma unroll
        for (int r = 0; r < 4; ++r) if (!val[r]) p[r] = -1e30f;
        float pm = fmaxf(fmaxf(p[0], p[1]), fmaxf(p[2], p[3]));
        pm = fmaxf(pm, __shfl_xor(pm, 16));
        pm = fmaxf(pm, __shfl_xor(pm, 32));
        if (pm > m + RESCALE_THR_LOG2) {
            float sc = exp2f(m - pm);
#pragma unroll
            for (int q = 0; q < 8; ++q) acc[q] *= sc;
            denom *= sc;
            m = pm;
        }
        float w0 = exp2f(p[0] - m);
        float w1 = exp2f(p[1] - m);
        float w2 = exp2f(p[2] - m);
        float w3 = exp2f(p[3] - m);
        denom += w0 + w1 + w2 + w3;
#pragma unroll
        for (int q = 0; q < 8; ++q) {
            unsigned int d0 = ((const unsigned int*)&xlu[0])[q >> 1];
            unsigned int d1 = ((const unsigned int*)&xlu[1])[q >> 1];
            unsigned int d2 = ((const unsigned int*)&xlu[2])[q >> 1];
            unsigned int d3 = ((const unsigned int*)&xlu[3])[q >> 1];
            float x0 = (q & 1) ? hhi(d0) : hlo(d0);
            float x1 = (q & 1) ? hhi(d1) : hlo(d1);
            float x2 = (q & 1) ? hhi(d2) : hlo(d2);
            float x3 = (q & 1) ? hhi(d3) : hlo(d3);
            acc[q] += w0 * x0 + w1 * x1 + w2 * x2 + w3 * x3;
        }
    }

    // cross-group (lk) reduces: groups hold disjoint edges, same dims
#pragma unroll
    for (int off = 16; off <= 32; off <<= 1) {
#pragma unroll
        for (int q = 0; q < 8; ++q) {
            acc[q] += __shfl_xor(acc[q], off);
            eps[q] += __shfl_xor(eps[q], off);
        }
        denom += __shfl_xor(denom, off);
    }

    // self-loop (last): loop_attr projection = mean of eproj
    float xliv[8];
    {
        uint4 xl4 = *(const uint4*)(xlh + (size_t)i * 64 + li * 4);
        xliv[0]=hlo(xl4.x); xliv[1]=hhi(xl4.x); xliv[2]=hlo(xl4.y); xliv[3]=hhi(xl4.y);
        xliv[4]=hlo(xl4.z); xliv[5]=hhi(xl4.z); xliv[6]=hlo(xl4.w); xliv[7]=hhi(xl4.w);
    }
    float invdeg = 1.f / fmaxf((float)cnt, 1.f);
    float ps = 0.f;
#pragma unroll
    for (int q = 0; q < 8; ++q) {
        float sv = xliv[q] + xriv[q] + eps[q] * invdeg;
        sv = fmaxf(sv, NEG_SLOPE * sv);
        ps += sv * attv[q];
    }
#pragma unroll
    for (int off = 1; off <= 8; off <<= 1) ps += __shfl_xor(ps, off);

    float mm = fmaxf(m, ps);
    float wf = exp2f(m - mm);
    float ws = exp2f(ps - mm);
    denom = denom * wf + ws;

    float bov[8];
    {
        const float4* bp = (const float4*)(bo_p + li * 8);
        float4 q0 = bp[0], q1 = bp[1];
        bov[0]=q0.x; bov[1]=q0.y; bov[2]=q0.z; bov[3]=q0.w;
        bov[4]=q1.x; bov[5]=q1.y; bov[6]=q1.z; bov[7]=q1.w;
    }
    float o[8];
#pragma unroll
    for (int q = 0; q < 8; ++q) {
        float a = acc[q] * wf + ws * xliv[q];
        float ox = a / denom + bov[q];
        o[q] = ox / (1.f + __expf(-ox));
    }
    if (lk == 0) {
        if (OUTH) {
            uint4 st = make_uint4(pkh(o[0], o[1]), pkh(o[2], o[3]),
                                  pkh(o[4], o[5]), pkh(o[6], o[7]));
            *(uint4*)(houth + (size_t)i * 64 + li * 4) = st;
        } else {
#pragma unroll
            for (int n = 0; n < 8; ++n)
                houtf[(size_t)i * 128 + li + 16 * n] = o[n];
        }
    }
}

// ---------------- host launch ----------------
extern "C" void kernel_launch(void* const* d_in, const int* in_sizes, int n_in,
                              void* d_out, int out_size, void* d_ws, size_t ws_size,
                              hipStream_t stream) {
    const float* x      = (const float*)d_in[0];
    const int*   ei     = (const int*)d_in[1];
    const float* ea     = (const float*)d_in[2];
    const float* W_emb  = (const float*)d_in[3];
    const float* b_emb  = (const float*)d_in[4];
    const float* Wl1    = (const float*)d_in[5];
    const float* bl1    = (const float*)d_in[6];
    const float* Wr1    = (const float*)d_in[7];
    const float* We1    = (const float*)d_in[8];
    const float* att1   = (const float*)d_in[9];
    const float* bo1    = (const float*)d_in[10];
    const float* Wl2    = (const float*)d_in[11];
    const float* bl2    = (const float*)d_in[12];
    const float* Wr2    = (const float*)d_in[13];
    const float* We2    = (const float*)d_in[14];
    const float* att2   = (const float*)d_in[15];
    const float* bo2    = (const float*)d_in[16];
    float* out = (float*)d_out;

    char* p = (char*)d_ws;
    auto carve = [&](size_t bytes) {
        void* q = (void*)p;
        p += (bytes + 255) / 256 * 256;
        return q;
    };
    unsigned int* hh  = (unsigned int*)carve((size_t)HIP_N * 64 * 4);
    unsigned int* xlh = (unsigned int*)carve((size_t)HIP_N * 64 * 4);
    unsigned int* xrh = (unsigned int*)carve((size_t)HIP_N * 64 * 4);
    unsigned int* ea_h = (unsigned int*)carve((size_t)HIP_E * 16 * 4);
    int*   deg      = (int*)carve((size_t)HIP_N * 4);
    int*   offs     = (int*)carve((size_t)(HIP_N + 1) * 4);
    int*   cursor   = (int*)carve((size_t)HIP_N * 4);
    int*   e_src    = (int*)carve((size_t)HIP_E * 4);
    int*   bsums    = (int*)carve((size_t)SCAN_NB * 4);
    unsigned short* Wt1 = (unsigned short*)carve(256 * 128 * 2);
    unsigned short* Wt2 = (unsigned short*)carve(256 * 128 * 2);
    float* b1       = (float*)carve(256 * 4);
    float* b2       = (float*)carve(256 * 4);
    uint4* WemB1    = (uint4*)carve(512 * 16);
    uint4* WemB2    = (uint4*)carve(512 * 16);
    float* attp1    = (float*)carve(128 * 4);
    float* bop1     = (float*)carve(128 * 4);
    float* attp2    = (float*)carve(128 * 4);
    float* bop2     = (float*)carve(128 * 4);

    k_prep<<<PREP_NB, 128, 0, stream>>>(W_emb, b_emb, Wl1, bl1, Wr1,
                                        Wl2, bl2, Wr2, We1, We2,
                                        att1, bo1, att2, bo2,
                                        Wt1, Wt2, b1, b2,
                                        WemB1, WemB2, attp1, bop1, attp2, bop2,
                                        deg);

    k_hist<<<(HIP_E + 255) / 256, 256, 0, stream>>>(ei, deg);
    k_scan1<<<SCAN_NB, 256, 0, stream>>>(deg, bsums);
    k_scan3<<<SCAN_NB, 1024, 0, stream>>>(deg, bsums, offs, cursor);

    // fat dispatch: layer-1 MFMA lin (composed weights, input x) + CSR scatter
    k_fat1<<<LINM + SCATB, 256, 0, stream>>>(x, Wt1, b1, xlh, xrh,
                                             ei, cursor, e_src, ea, ea_h);

    // ----- layer 1 (h written permuted packed f16) -----
    k_node_mfma<1><<<HIP_N, 64, 0, stream>>>(offs, e_src, ea_h, WemB1, attp1,
                                             xlh, xrh, bop1, hh, nullptr);
    // ----- layer 2 -----
    k_linm<<<LINM, 256, 0, stream>>>(hh, Wt2, b2, xlh, xrh);
    k_node_mfma<0><<<HIP_N, 64, 0, stream>>>(offs, e_src, ea_h, WemB2, attp2,
                                             xlh, xrh, bop2, nullptr, out);
}

// Round 20
// 432.689 us; speedup vs baseline: 1.0284x; 1.0284x over previous
//
#include <hip/hip_runtime.h>
#include <hip/hip_bf16.h>
#include <math.h>

// HelicalGNNFrontend: 2-layer GATv2 (heads=1, self-loops, mean loop edge_attr)
// N=50000, E=800000, NODE_DIM=HID=128, EDGE_DIM=32.
//
// Round 20: revert fused kernel to R18 fdot2 form (R19's MFMA rebuild was a
// wash: eproj MACs off the VALU but VGPR 112 collapsed occupancy 58->21%).
// Single change vs R18: 3-wide edge pipeline (3 concurrent gathers + 3
// interleaved shfl chains; +8 VGPR at 40-base keeps occupancy, unlike R10's
// confounded attempt at 88-base). All else frozen from R18.

#define HIP_N 50000
#define HIP_E 800000
#define HIP_H 128
#define HIP_ED 32
#define NEG_SLOPE 0.2f
#define RESCALE_THR_LOG2 11.5416f   // 8 / ln2
#define LINM 3125                   // 50000 / 16 M-tiles
#define SCATB ((HIP_E + 255) / 256) // 3125 scatter blocks
#define INV_LN2 1.4426950408889634f

typedef __fp16 h2 __attribute__((ext_vector_type(2)));
typedef _Float16 half8 __attribute__((ext_vector_type(8)));
typedef float f32x4 __attribute__((ext_vector_type(4)));

__device__ __forceinline__ h2 u2h(unsigned int u) {
    union { unsigned int u; h2 h; } c; c.u = u; return c.h;
}
__device__ __forceinline__ unsigned int pkh(float a, float b) {
    union { h2 h; unsigned int u; } c;
    c.h = __builtin_amdgcn_cvt_pkrtz(a, b);
    return c.u;
}
__device__ __forceinline__ float2 h2f(unsigned int u) {
    h2 h = u2h(u);
    return make_float2((float)h.x, (float)h.y);
}
__device__ __forceinline__ half8 u4h8(uint4 u) {
    union { uint4 u; half8 h; } c; c.u = u; return c.h;
}

__device__ __forceinline__ int fetch_idx(const int* __restrict__ ei, int is32, long long pos) {
    return is32 ? ei[pos] : ei[2 * pos];  // little-endian low word for int64
}

// per-wave edge-dtype detect: probe ei[2e+1] (valid flat index in BOTH
// layouts). int64 -> high words, all zero. int32 -> node ids, ~never all 0.
__device__ __forceinline__ int wave_is32(const int* __restrict__ ei, int e) {
    int probe = (e < HIP_E) ? ei[2 * (long long)e + 1] : 0;
    return __any(probe != 0);
}

// ---------------- mega prep kernel (128 threads/block) ----------------
// blocks [0,256): compose W_emb@{Wl1,Wr1} row -> Wt1 transposed f16
// blocks 256..259: biases
// blocks [260,388): layer-2 weight transpose -> Wt2 f16
// blocks [388,420): We1/We2 pack -> Wepk1/2
// blocks [420, ...): zero deg
#define PREP_NB (420 + (HIP_N + 127) / 128)

__global__ __launch_bounds__(128) void k_prep(
    const float* __restrict__ Wemb, const float* __restrict__ bemb,
    const float* __restrict__ Wl1, const float* __restrict__ bl1,
    const float* __restrict__ Wr1,
    const float* __restrict__ Wl2, const float* __restrict__ bl2,
    const float* __restrict__ Wr2,
    const float* __restrict__ We1, const float* __restrict__ We2,
    unsigned short* __restrict__ Wt1, unsigned short* __restrict__ Wt2,
    float* __restrict__ b1, float* __restrict__ b2,
    unsigned int* __restrict__ Wepk1, unsigned int* __restrict__ Wepk2,
    int* __restrict__ deg) {
    int b = blockIdx.x, t = threadIdx.x;
    if (b < 256) {
        int r = b & 127;
        const float* W = (b < 128) ? Wl1 : Wr1;
        int nofs = (b < 128) ? 0 : 128;
        float acc = 0.f;
        for (int k = 0; k < 128; ++k) acc += Wemb[r * 128 + k] * W[k * 128 + t];
        union { __fp16 h; unsigned short s; } cv;
        cv.h = (__fp16)acc;
        Wt1[(size_t)(nofs + t) * 128 + r] = cv.s;   // Wt1[n][k] = Wf[k][n]
    } else if (b == 256) {
        float acc = bl1[t];
        for (int k = 0; k < 128; ++k) acc += bemb[k] * Wl1[k * 128 + t];
        b1[t] = acc;
    } else if (b == 257) {
        float acc = 0.f;
        for (int k = 0; k < 128; ++k) acc += bemb[k] * Wr1[k * 128 + t];
        b1[128 + t] = acc;
    } else if (b == 258) {
        b2[t] = bl2[t];
    } else if (b == 259) {
        b2[128 + t] = 0.f;
    } else if (b < 388) {
        int k = b - 260;                            // row of Wl2/Wr2
        float vl = Wl2[k * 128 + t], vr = Wr2[k * 128 + t];
        union { __fp16 h; unsigned short s; } c1, c2;
        c1.h = (__fp16)vl; c2.h = (__fp16)vr;
        Wt2[(size_t)t * 128 + k] = c1.s;
        Wt2[(size_t)(128 + t) * 128 + k] = c2.s;
    } else if (b < 420) {
        int idx = (b - 388) * 128 + t;              // [0, 4096)
        const float* We = (idx < 2048) ? We1 : We2;
        unsigned int* P = (idx < 2048) ? Wepk1 : Wepk2;
        int r = idx & 2047;
        int d2 = r >> 7, rem = r & 127;
        int j = rem >> 6, tt = rem & 63;
        int col = 2 * tt + j;
        P[r] = pkh(We[(2 * d2) * 128 + col], We[(2 * d2 + 1) * 128 + col]);
    } else {
        int i = (b - 420) * 128 + t;
        if (i < HIP_N) deg[i] = 0;
    }
}

// ---------------- CSR build ----------------
__global__ void k_hist(const int* __restrict__ ei, int* __restrict__ deg) {
    int e = blockIdx.x * blockDim.x + threadIdx.x;
    int is32 = wave_is32(ei, e);
    if (e < HIP_E) {
        int d = fetch_idx(ei, is32, (long long)HIP_E + e);
        atomicAdd(&deg[d], 1);
    }
}

#define SCAN_TILE 1024
#define SCAN_NB ((HIP_N + SCAN_TILE - 1) / SCAN_TILE)   // 49

__global__ __launch_bounds__(256) void k_scan1(const int* __restrict__ deg,
                                               int* __restrict__ bsums) {
    __shared__ int ws[4];
    int b = blockIdx.x, t = threadIdx.x;
    int base = b * SCAN_TILE;
    int v = 0;
#pragma unroll
    for (int j = 0; j < 4; ++j) {
        int i = base + t + 256 * j;
        if (i < HIP_N) v += deg[i];
    }
#pragma unroll
    for (int off = 32; off > 0; off >>= 1) v += __shfl_xor(v, off);
    int lane = t & 63, wid = t >> 6;
    if (lane == 0) ws[wid] = v;
    __syncthreads();
    if (t == 0) bsums[b] = ws[0] + ws[1] + ws[2] + ws[3];
}

// scan3 with folded scan2: block computes its own bsums prefix
__global__ __launch_bounds__(1024) void k_scan3(const int* __restrict__ deg,
                                                const int* __restrict__ bsums,
                                                int* __restrict__ offs,
                                                int* __restrict__ cursor) {
    __shared__ int wsum[16];
    __shared__ int bbase_sh;
    int b = blockIdx.x, t = threadIdx.x;
    int i = b * SCAN_TILE + t;
    int lane = t & 63, wid = t >> 6;
    if (wid == 0) {                      // prefix of bsums[0..b-1]
        int v = (lane < SCAN_NB && lane < b) ? bsums[lane] : 0;
#pragma unroll
        for (int off = 32; off > 0; off >>= 1) v += __shfl_xor(v, off);
        if (lane == 0) bbase_sh = v;
    }
    int v = (i < HIP_N) ? deg[i] : 0;
    int incl = v;
#pragma unroll
    for (int off = 1; off < 64; off <<= 1) {
        int u = __shfl_up(incl, off);
        if (lane >= off) incl += u;
    }
    if (lane == 63) wsum[wid] = incl;
    __syncthreads();
    if (wid == 0 && lane < 16) {
        int w = wsum[lane];
#pragma unroll
        for (int off = 1; off < 16; off <<= 1) {
            int u = __shfl_up(w, off);
            if (lane >= off) w += u;
        }
        wsum[lane] = w;   // inclusive over waves
    }
    __syncthreads();
    int baseadd = bbase_sh + (wid > 0 ? wsum[wid - 1] : 0);
    int excl = baseadd + incl - v;
    if (i < HIP_N) {
        offs[i] = excl;
        cursor[i] = excl;
        if (i == HIP_N - 1) offs[HIP_N] = excl + v;
    }
}

// ---------------- MFMA dual-GEMM body (templated A dtype) ----------------
// out[xl|xr] = A[50k,128] @ Wt^T (Wt [256][128] f16) + bias[256]
template <bool AHALF>
__device__ __forceinline__ void linm_body(const float* __restrict__ Af,
                                          const unsigned int* __restrict__ Ah,
                                          const unsigned short* __restrict__ Wt,
                                          const float* __restrict__ bias,
                                          unsigned int* __restrict__ xlh,
                                          unsigned int* __restrict__ xrh, int blk) {
    int tid = threadIdx.x;
    int wid = tid >> 6, l = tid & 63;
    int li = l & 15, lk = l >> 4;          // A row / C col = li; k-group = lk
    int rowA = blk * 16 + li;

    f32x4 acc0 = {0.f, 0.f, 0.f, 0.f};
    f32x4 acc1 = {0.f, 0.f, 0.f, 0.f};
    f32x4 acc2 = {0.f, 0.f, 0.f, 0.f};
    f32x4 acc3 = {0.f, 0.f, 0.f, 0.f};

#pragma unroll
    for (int ks = 0; ks < 4; ++ks) {
        int kb = ks * 32 + lk * 8;
        half8 afrag;
        if (AHALF) {
            afrag = u4h8(*(const uint4*)(Ah + (size_t)rowA * 64 + (kb >> 1)));
        } else {
            const float4* ap = (const float4*)(Af + (size_t)rowA * 128 + kb);
            float4 a0 = ap[0], a1 = ap[1];
            afrag = u4h8(make_uint4(pkh(a0.x, a0.y), pkh(a0.z, a0.w),
                                    pkh(a1.x, a1.y), pkh(a1.z, a1.w)));
        }
        int nbase = wid * 64 + li;
        half8 b0 = u4h8(*(const uint4*)(Wt + (size_t)(nbase +  0) * 128 + kb));
        half8 b1 = u4h8(*(const uint4*)(Wt + (size_t)(nbase + 16) * 128 + kb));
        half8 b2 = u4h8(*(const uint4*)(Wt + (size_t)(nbase + 32) * 128 + kb));
        half8 b3 = u4h8(*(const uint4*)(Wt + (size_t)(nbase + 48) * 128 + kb));
        acc0 = __builtin_amdgcn_mfma_f32_16x16x32_f16(afrag, b0, acc0, 0, 0, 0);
        acc1 = __builtin_amdgcn_mfma_f32_16x16x32_f16(afrag, b1, acc1, 0, 0, 0);
        acc2 = __builtin_amdgcn_mfma_f32_16x16x32_f16(afrag, b2, acc2, 0, 0, 0);
        acc3 = __builtin_amdgcn_mfma_f32_16x16x32_f16(afrag, b3, acc3, 0, 0, 0);
    }

    bool even = !(l & 1);
#pragma unroll
    for (int nt = 0; nt < 4; ++nt) {
        f32x4 a = (nt == 0) ? acc0 : (nt == 1) ? acc1 : (nt == 2) ? acc2 : acc3;
        int n = wid * 64 + nt * 16 + li;
        float bb = bias[n];
        unsigned int* outp = (n < 128) ? xlh : xrh;
        int nn = n & 127;
#pragma unroll
        for (int r = 0; r < 4; ++r) {
            int rowg = blk * 16 + lk * 4 + r;
            float v = a[r] + bb;
            float v1 = __shfl_down(v, 1);
            if (even) outp[(size_t)rowg * 64 + (nn >> 1)] = pkh(v, v1);
        }
    }
}

// scatter body: e_src[pos]=src, ea_h[pos]= half2-packed ea row (64B)
__device__ __forceinline__ void scatter_body(const int* __restrict__ ei, int is32,
                                             int* __restrict__ cursor,
                                             int* __restrict__ e_src,
                                             const float* __restrict__ ea,
                                             unsigned int* __restrict__ ea_h, int e) {
    if (e < HIP_E) {
        int s = fetch_idx(ei, is32, e);
        int d = fetch_idx(ei, is32, (long long)HIP_E + e);
        int pos = atomicAdd(&cursor[d], 1);
        e_src[pos] = s;
        const float4* src4 = (const float4*)(ea + (size_t)e * HIP_ED);
        float4 s0 = src4[0], s1 = src4[1], s2 = src4[2], s3 = src4[3];
        float4 s4 = src4[4], s5 = src4[5], s6 = src4[6], s7 = src4[7];
        uint4* dst = (uint4*)(ea_h + (size_t)pos * 16);
        dst[0] = make_uint4(pkh(s0.x, s0.y), pkh(s0.z, s0.w),
                            pkh(s1.x, s1.y), pkh(s1.z, s1.w));
        dst[1] = make_uint4(pkh(s2.x, s2.y), pkh(s2.z, s2.w),
                            pkh(s3.x, s3.y), pkh(s3.z, s3.w));
        dst[2] = make_uint4(pkh(s4.x, s4.y), pkh(s4.z, s4.w),
                            pkh(s5.x, s5.y), pkh(s5.z, s5.w));
        dst[3] = make_uint4(pkh(s6.x, s6.y), pkh(s6.z, s6.w),
                            pkh(s7.x, s7.y), pkh(s7.z, s7.w));
    }
}

// fat kernel: blocks [0, LINM) do layer-1 MFMA lin; rest scatter
__global__ __launch_bounds__(256) void k_fat1(
    const float* __restrict__ x, const unsigned short* __restrict__ Wt1,
    const float* __restrict__ b1,
    unsigned int* __restrict__ xlh, unsigned int* __restrict__ xrh,
    const int* __restrict__ ei,
    int* __restrict__ cursor, int* __restrict__ e_src,
    const float* __restrict__ ea, unsigned int* __restrict__ ea_h) {
    if (blockIdx.x < LINM) {
        linm_body<false>(x, nullptr, Wt1, b1, xlh, xrh, blockIdx.x);
    } else {
        int e = (blockIdx.x - LINM) * 256 + threadIdx.x;
        int is32 = wave_is32(ei, e);
        scatter_body(ei, is32, cursor, e_src, ea, ea_h, e);
    }
}

// layer-2 lin: A = packed-f16 h
__global__ __launch_bounds__(256) void k_linm(const unsigned int* __restrict__ hh,
                                              const unsigned short* __restrict__ Wt,
                                              const float* __restrict__ bias,
                                              unsigned int* __restrict__ xlh,
                                              unsigned int* __restrict__ xrh) {
    linm_body<true>(nullptr, hh, Wt, bias, xlh, xrh, blockIdx.x);
}

// ---------------- fused per-node online softmax + aggregation ----------------
// ONE 64-thread block per node; scalar s_load edge stream; f16 packed xl/xr
// gathers; 32x fdot2 eproj; exp2 logits; THREE-wide edge pipeline.
// OUTH=1: write packed f16 (inter-layer h); OUTH=0: write fp32 (final out).
template <int OUTH>
__global__ __launch_bounds__(64) void k_node_fused(
    const int* __restrict__ offs, const int* __restrict__ e_src,
    const unsigned int* __restrict__ ea_h,
    const unsigned int* __restrict__ Wepk, const float* __restrict__ att,
    const unsigned int* __restrict__ xlh, const unsigned int* __restrict__ xrh,
    const float* __restrict__ bo,
    unsigned int* __restrict__ houth, float* __restrict__ houtf) {
    int i = blockIdx.x;           // uniform node id
    int t = threadIdx.x;          // lane, owns feature dims (2t, 2t+1)

    h2 wx00 = u2h(Wepk[ 0*128 + t]),      wy00 = u2h(Wepk[ 0*128 + 64 + t]);
    h2 wx01 = u2h(Wepk[ 1*128 + t]),      wy01 = u2h(Wepk[ 1*128 + 64 + t]);
    h2 wx02 = u2h(Wepk[ 2*128 + t]),      wy02 = u2h(Wepk[ 2*128 + 64 + t]);
    h2 wx03 = u2h(Wepk[ 3*128 + t]),      wy03 = u2h(Wepk[ 3*128 + 64 + t]);
    h2 wx04 = u2h(Wepk[ 4*128 + t]),      wy04 = u2h(Wepk[ 4*128 + 64 + t]);
    h2 wx05 = u2h(Wepk[ 5*128 + t]),      wy05 = u2h(Wepk[ 5*128 + 64 + t]);
    h2 wx06 = u2h(Wepk[ 6*128 + t]),      wy06 = u2h(Wepk[ 6*128 + 64 + t]);
    h2 wx07 = u2h(Wepk[ 7*128 + t]),      wy07 = u2h(Wepk[ 7*128 + 64 + t]);
    h2 wx08 = u2h(Wepk[ 8*128 + t]),      wy08 = u2h(Wepk[ 8*128 + 64 + t]);
    h2 wx09 = u2h(Wepk[ 9*128 + t]),      wy09 = u2h(Wepk[ 9*128 + 64 + t]);
    h2 wx10 = u2h(Wepk[10*128 + t]),      wy10 = u2h(Wepk[10*128 + 64 + t]);
    h2 wx11 = u2h(Wepk[11*128 + t]),      wy11 = u2h(Wepk[11*128 + 64 + t]);
    h2 wx12 = u2h(Wepk[12*128 + t]),      wy12 = u2h(Wepk[12*128 + 64 + t]);
    h2 wx13 = u2h(Wepk[13*128 + t]),      wy13 = u2h(Wepk[13*128 + 64 + t]);
    h2 wx14 = u2h(Wepk[14*128 + t]),      wy14 = u2h(Wepk[14*128 + 64 + t]);
    h2 wx15 = u2h(Wepk[15*128 + t]),      wy15 = u2h(Wepk[15*128 + 64 + t]);

    float2 attv = ((const float2*)att)[t];
    attv.x *= INV_LN2; attv.y *= INV_LN2;   // exp2-domain logits
    float2 bov  = ((const float2*)bo)[t];
    float2 xri  = h2f(xrh[(size_t)i * 64 + t]);
    float2 xli  = h2f(xlh[(size_t)i * 64 + t]);

    float m = -1e30f;
    float denom = 0.f;
    float accx = 0.f, accy = 0.f;
    float epsx = 0.f, epsy = 0.f;   // sum of per-edge eproj (for self-loop)

    int o0 = offs[i], o1 = offs[i + 1];     // uniform -> s_load
    int cnt = o1 - o0;
    int trips = cnt / 3;

#define DOTP(EX, EY, U, K)                                            \
    EX = __builtin_amdgcn_fdot2(u2h(U), wx##K, EX, false);            \
    EY = __builtin_amdgcn_fdot2(u2h(U), wy##K, EY, false);

#define EPROJ(EX, EY, P)                                              \
    {                                                                 \
        uint4 q0 = ((const uint4*)(P))[0];                            \
        uint4 q1 = ((const uint4*)(P))[1];                            \
        uint4 q2 = ((const uint4*)(P))[2];                            \
        uint4 q3 = ((const uint4*)(P))[3];                            \
        DOTP(EX, EY, q0.x, 00) DOTP(EX, EY, q0.y, 01)                 \
        DOTP(EX, EY, q0.z, 02) DOTP(EX, EY, q0.w, 03)                 \
        DOTP(EX, EY, q1.x, 04) DOTP(EX, EY, q1.y, 05)                 \
        DOTP(EX, EY, q1.z, 06) DOTP(EX, EY, q1.w, 07)                 \
        DOTP(EX, EY, q2.x, 08) DOTP(EX, EY, q2.y, 09)                 \
        DOTP(EX, EY, q2.z, 10) DOTP(EX, EY, q2.w, 11)                 \
        DOTP(EX, EY, q3.x, 12) DOTP(EX, EY, q3.y, 13)                 \
        DOTP(EX, EY, q3.z, 14) DOTP(EX, EY, q3.w, 15)                 \
    }

    // triple-ahead prefetch of the three xl gathers (one dword each)
    unsigned int uA = 0, uB = 0, uC = 0;
    if (trips > 0) {
        int s0 = e_src[o0];                 // uniform -> s_load
        int s1 = e_src[o0 + 1];
        int s2 = e_src[o0 + 2];
        uA = xlh[(size_t)s0 * 64 + t];
        uB = xlh[(size_t)s1 * 64 + t];
        uC = xlh[(size_t)s2 * 64 + t];
    }

    for (int tp = 0; tp < trips; ++tp) {
        int e = o0 + 3 * tp;
        float2 x0 = h2f(uA), x1 = h2f(uB), x2 = h2f(uC);
        if (tp + 1 < trips) {               // prefetch next triple
            int s0 = e_src[e + 3];
            int s1 = e_src[e + 4];
            int s2 = e_src[e + 5];
            uA = xlh[(size_t)s0 * 64 + t];
            uB = xlh[(size_t)s1 * 64 + t];
            uC = xlh[(size_t)s2 * 64 + t];
        }
        const unsigned int* er = ea_h + (size_t)e * 16;   // uniform (3 rows, 48 dw)
        float ex0 = 0.f, ey0 = 0.f, ex1 = 0.f, ey1 = 0.f, ex2 = 0.f, ey2 = 0.f;
        EPROJ(ex0, ey0, er)
        EPROJ(ex1, ey1, er + 16)
        EPROJ(ex2, ey2, er + 32)
        epsx += ex0 + ex1 + ex2; epsy += ey0 + ey1 + ey2;
        float vx0 = x0.x + xri.x + ex0, vy0 = x0.y + xri.y + ey0;
        float vx1 = x1.x + xri.x + ex1, vy1 = x1.y + xri.y + ey1;
        float vx2 = x2.x + xri.x + ex2, vy2 = x2.y + xri.y + ey2;
        vx0 = fmaxf(vx0, NEG_SLOPE * vx0);
        vy0 = fmaxf(vy0, NEG_SLOPE * vy0);
        vx1 = fmaxf(vx1, NEG_SLOPE * vx1);
        vy1 = fmaxf(vy1, NEG_SLOPE * vy1);
        vx2 = fmaxf(vx2, NEG_SLOPE * vx2);
        vy2 = fmaxf(vy2, NEG_SLOPE * vy2);
        float p0 = vx0 * attv.x + vy0 * attv.y;
        float p1 = vx1 * attv.x + vy1 * attv.y;
        float p2 = vx2 * attv.x + vy2 * attv.y;
#pragma unroll
        for (int off = 32; off > 0; off >>= 1) {   // interleaved chains
            p0 += __shfl_xor(p0, off);
            p1 += __shfl_xor(p1, off);
            p2 += __shfl_xor(p2, off);
        }
        float pm = fmaxf(fmaxf(p0, p1), p2);
        if (pm > m + RESCALE_THR_LOG2) {    // defer-max rescale (wave-uniform)
            float sc = exp2f(m - pm);
            accx *= sc; accy *= sc; denom *= sc;
            m = pm;
        }
        float wA = exp2f(p0 - m);
        float wB = exp2f(p1 - m);
        float wC = exp2f(p2 - m);
        accx += wA * x0.x + wB * x1.x + wC * x2.x;
        accy += wA * x0.y + wB * x1.y + wC * x2.y;
        denom += wA + wB + wC;
    }

    for (int e = o0 + 3 * trips; e < o1; ++e) {     // tail (0..2 edges)
        int s = e_src[e];
        float2 x0 = h2f(xlh[(size_t)s * 64 + t]);
        const unsigned int* er = ea_h + (size_t)e * 16;
        float ex = 0.f, ey = 0.f;
        EPROJ(ex, ey, er)
        epsx += ex; epsy += ey;
        float vx = x0.x + xri.x + ex;
        float vy = x0.y + xri.y + ey;
        vx = fmaxf(vx, NEG_SLOPE * vx);
        vy = fmaxf(vy, NEG_SLOPE * vy);
        float p = vx * attv.x + vy * attv.y;
#pragma unroll
        for (int off = 32; off > 0; off >>= 1) p += __shfl_xor(p, off);
        if (p > m + RESCALE_THR_LOG2) {
            float sc = exp2f(m - p);
            accx *= sc; accy *= sc; denom *= sc;
            m = p;
        }
        float w = exp2f(p - m);
        accx += w * x0.x;
        accy += w * x0.y;
        denom += w;
    }
#undef EPROJ
#undef DOTP

    // ---- self-loop (last): loop_attr projection = mean of eproj ----
    float invdeg = 1.f / fmaxf((float)cnt, 1.f);
    float sx = xli.x + xri.x + epsx * invdeg;
    float sy = xli.y + xri.y + epsy * invdeg;
    sx = fmaxf(sx, NEG_SLOPE * sx);
    sy = fmaxf(sy, NEG_SLOPE * sy);
    float ps = sx * attv.x + sy * attv.y;
#pragma unroll
    for (int off = 32; off > 0; off >>= 1) ps += __shfl_xor(ps, off);

    float mm = fmaxf(m, ps);
    float wf = exp2f(m - mm);
    float ws = exp2f(ps - mm);
    denom = denom * wf + ws;
    accx = accx * wf + ws * xli.x;
    accy = accy * wf + ws * xli.y;

    float ox = accx / denom + bov.x;
    float oy = accy / denom + bov.y;
    float sox = ox / (1.f + __expf(-ox));
    float soy = oy / (1.f + __expf(-oy));
    if (OUTH) {
        houth[(size_t)i * 64 + t] = pkh(sox, soy);
    } else {
        float2 o; o.x = sox; o.y = soy;
        ((float2*)(houtf + (size_t)i * HIP_H))[t] = o;
    }
}

// ---------------- host launch ----------------
extern "C" void kernel_launch(void* const* d_in, const int* in_sizes, int n_in,
                              void* d_out, int out_size, void* d_ws, size_t ws_size,
                              hipStream_t stream) {
    const float* x      = (const float*)d_in[0];
    const int*   ei     = (const int*)d_in[1];
    const float* ea     = (const float*)d_in[2];
    const float* W_emb  = (const float*)d_in[3];
    const float* b_emb  = (const float*)d_in[4];
    const float* Wl1    = (const float*)d_in[5];
    const float* bl1    = (const float*)d_in[6];
    const float* Wr1    = (const float*)d_in[7];
    const float* We1    = (const float*)d_in[8];
    const float* att1   = (const float*)d_in[9];
    const float* bo1    = (const float*)d_in[10];
    const float* Wl2    = (const float*)d_in[11];
    const float* bl2    = (const float*)d_in[12];
    const float* Wr2    = (const float*)d_in[13];
    const float* We2    = (const float*)d_in[14];
    const float* att2   = (const float*)d_in[15];
    const float* bo2    = (const float*)d_in[16];
    float* out = (float*)d_out;

    char* p = (char*)d_ws;
    auto carve = [&](size_t bytes) {
        void* q = (void*)p;
        p += (bytes + 255) / 256 * 256;
        return q;
    };
    unsigned int* hh  = (unsigned int*)carve((size_t)HIP_N * 64 * 4);
    unsigned int* xlh = (unsigned int*)carve((size_t)HIP_N * 64 * 4);
    unsigned int* xrh = (unsigned int*)carve((size_t)HIP_N * 64 * 4);
    unsigned int* ea_h = (unsigned int*)carve((size_t)HIP_E * 16 * 4);
    int*   deg      = (int*)carve((size_t)HIP_N * 4);
    int*   offs     = (int*)carve((size_t)(HIP_N + 1) * 4);
    int*   cursor   = (int*)carve((size_t)HIP_N * 4);
    int*   e_src    = (int*)carve((size_t)HIP_E * 4);
    int*   bsums    = (int*)carve((size_t)SCAN_NB * 4);
    unsigned int* Wepk1 = (unsigned int*)carve(2048 * 4);
    unsigned int* Wepk2 = (unsigned int*)carve(2048 * 4);
    unsigned short* Wt1 = (unsigned short*)carve(256 * 128 * 2);
    unsigned short* Wt2 = (unsigned short*)carve(256 * 128 * 2);
    float* b1       = (float*)carve(256 * 4);
    float* b2       = (float*)carve(256 * 4);

    // ONE prep dispatch: compose->Wt1(f16,T), Wt2 transpose, biases,
    // We packs, deg zeroing (edge dtype self-detected per wave)
    k_prep<<<PREP_NB, 128, 0, stream>>>(W_emb, b_emb, Wl1, bl1, Wr1,
                                        Wl2, bl2, Wr2, We1, We2,
                                        Wt1, Wt2, b1, b2,
                                        Wepk1, Wepk2, deg);

    k_hist<<<(HIP_E + 255) / 256, 256, 0, stream>>>(ei, deg);
    k_scan1<<<SCAN_NB, 256, 0, stream>>>(deg, bsums);
    k_scan3<<<SCAN_NB, 1024, 0, stream>>>(deg, bsums, offs, cursor);

    // fat dispatch: layer-1 MFMA lin (composed weights, input x) + CSR scatter
    k_fat1<<<LINM + SCATB, 256, 0, stream>>>(x, Wt1, b1, xlh, xrh,
                                             ei, cursor, e_src, ea, ea_h);

    // ----- layer 1 (h written packed f16) -----
    k_node_fused<1><<<HIP_N, 64, 0, stream>>>(offs, e_src, ea_h, Wepk1, att1,
                                              xlh, xrh, bo1, hh, nullptr);
    // ----- layer 2 -----
    k_linm<<<LINM, 256, 0, stream>>>(hh, Wt2, b2, xlh, xrh);
    k_node_fused<0><<<HIP_N, 64, 0, stream>>>(offs, e_src, ea_h, Wepk2, att2,
                                              xlh, xrh, bo2, nullptr, out);
}